// Round 4
// baseline (300.356 us; speedup 1.0000x reference)
//
#include <hip/hip_runtime.h>
#include <math.h>

// ---------------------------------------------------------------------------
// RoutingNet round 4: FMA-dense conv layouts (lane=oc, wave-uniform windows,
// coalesced transposed weights), b128-aligned padded LDS, fused tail
// (score+lsm), low-sync routing. 10 kernels.
// ---------------------------------------------------------------------------

#define BN_SCALE rsqrtf(1.0f + 1e-5f)

// Transpose w2,w3,w4 OIHW -> [ic][tap][oc]; zero t1.
// 18432 + 73728 + 294912 + 256000 = 643072 = 2512*256
__global__ void k_pre(const float* __restrict__ w2, const float* __restrict__ w3,
                      const float* __restrict__ w4, float* __restrict__ w2t,
                      float* __restrict__ w3t, float* __restrict__ w4t,
                      float* __restrict__ t1z) {
  int i = blockIdx.x * 256 + threadIdx.x;
  if (i < 18432) {                        // w2: OC=64, IC=32
    int oc = i & 63; int r = i >> 6; int tap = r % 9; int ic = r / 9;
    w2t[i] = w2[(oc * 32 + ic) * 9 + tap];
  } else if (i < 92160) {                 // w3: OC=128, IC=64
    int j = i - 18432;
    int oc = j & 127; int r = j >> 7; int tap = r % 9; int ic = r / 9;
    w3t[j] = w3[(oc * 64 + ic) * 9 + tap];
  } else if (i < 387072) {                // w4: OC=256, IC=128
    int j = i - 92160;
    int oc = j & 255; int r = j >> 8; int tap = r % 9; int ic = r / 9;
    w4t[j] = w4[(oc * 128 + ic) * 9 + tap];
  } else {
    t1z[i - 387072] = 0.f;
  }
}

// Block 0: 1->16ch, 128x128 -s2-> 64x64 -pool-> 32x32. Grid 1000 (img x 4 bands).
// LDS padded to stride 132, col+1 shift -> aligned b128 window reads, no edge
// checks in the inner loop.
__global__ void k_block0(const float* __restrict__ sup, const float* __restrict__ qry,
                         const float* __restrict__ w, const float* __restrict__ g,
                         const float* __restrict__ bb, float* __restrict__ out) {
  __shared__ float simg[33 * 132];   // 17.4 KB
  int img = blockIdx.x >> 2, band = blockIdx.x & 3;
  const float* in = (img < 100) ? (sup + (size_t)img * 16384)
                                : (qry + (size_t)(img - 100) * 16384);
  int t = threadIdx.x;
  int row0 = band * 32 - 1;
  if (t < 33) simg[t * 132] = 0.f;                 // left pad column
  for (int i = t; i < 33 * 128; i += 256) {
    int r = i >> 7, cc = i & 127;
    int ry = row0 + r;
    simg[r * 132 + cc + 1] = (ry >= 0) ? in[ry * 128 + cc] : 0.f;
  }
  __syncthreads();

  int lane = t & 63, wid = t >> 6;
  int ox = lane & 31, oyh = lane >> 5;
  int oc0 = wid * 4;
  float wv[36], sc[4], bs[4];
#pragma unroll
  for (int j = 0; j < 4; j++) {
#pragma unroll
    for (int k = 0; k < 9; k++) wv[j * 9 + k] = w[(oc0 + j) * 9 + k];
    sc[j] = g[oc0 + j] * BN_SCALE;
    bs[j] = bb[oc0 + j];
  }
#pragma unroll
  for (int oyy = 0; oyy < 4; oyy++) {
    int oy = oyy * 2 + oyh;
    float win[25];
#pragma unroll
    for (int d = 0; d < 5; d++) {
      const float* rp = simg + (4 * oy + d) * 132 + 4 * ox;
      float4 r4 = *(const float4*)rp;
      win[d * 5 + 0] = r4.x; win[d * 5 + 1] = r4.y;
      win[d * 5 + 2] = r4.z; win[d * 5 + 3] = r4.w;
      win[d * 5 + 4] = rp[4];
    }
#pragma unroll
    for (int j = 0; j < 4; j++) {
      float m = -1e30f;
#pragma unroll
      for (int py = 0; py < 2; py++)
#pragma unroll
        for (int px = 0; px < 2; px++) {
          float c = 0.f;
#pragma unroll
          for (int ky = 0; ky < 3; ky++)
#pragma unroll
            for (int kx = 0; kx < 3; kx++)
              c = fmaf(win[(2 * py + ky) * 5 + (2 * px + kx)], wv[j * 9 + ky * 3 + kx], c);
          m = fmaxf(m, fmaf(c, sc[j], bs[j]));
        }
      int OY = band * 8 + oy;
      out[(((size_t)img * 16 + oc0 + j) * 32 + OY) * 32 + ox] = fmaxf(m, 0.f);
    }
  }
}

// Block 1: 16->32ch, 32x32 -s2-> 16x16 -pool-> 8x8.
// Grid 500 (img x 2 row-halves), 256 thr = 32 pos x 8 oc-groups (4 oc each).
__global__ void k_block1(const float* __restrict__ a0, const float* __restrict__ w,
                         const float* __restrict__ g, const float* __restrict__ bb,
                         float* __restrict__ out) {
  __shared__ float sIn[16 * 17 * 36];   // 39.2 KB, col shift +1, stride 36
  __shared__ float wl[16 * 32 * 12];    // 24.6 KB
  int b = blockIdx.x;
  int img = b >> 1, OY0 = (b & 1) * 4;
  int R0 = OY0 * 4 - 1;
  int t = threadIdx.x;
  const float* in = a0 + (size_t)img * 16384;
  for (int i = t; i < 9792; i += 256) {
    int c = i % 36; int rr = (i / 36) % 17; int ic = i / 612;
    int gr = R0 + rr, gc = c - 1;
    sIn[i] = (c >= 1 && c <= 32 && gr >= 0) ? in[ic * 1024 + gr * 32 + gc] : 0.f;
  }
  for (int j = t; j < 4608; j += 256) {
    int tap = j % 9; int r = j / 9; int ocl = r & 31; int ic = r >> 5;
    wl[ic * 384 + ocl * 12 + tap] = w[ocl * 144 + ic * 9 + tap];
  }
  __syncthreads();

  int pos = t & 31, og = t >> 5;
  int oxl = pos & 7, oyl = pos >> 3;
  float acc[4][4];
#pragma unroll
  for (int j = 0; j < 4; j++)
#pragma unroll
    for (int p = 0; p < 4; p++) acc[j][p] = 0.f;

  for (int ic = 0; ic < 16; ic++) {
    float win[25];
#pragma unroll
    for (int d = 0; d < 5; d++) {
      const float* rp = sIn + ic * 612 + (4 * oyl + d) * 36 + 4 * oxl;
      float4 r4 = *(const float4*)rp;
      win[d * 5 + 0] = r4.x; win[d * 5 + 1] = r4.y;
      win[d * 5 + 2] = r4.z; win[d * 5 + 3] = r4.w;
      win[d * 5 + 4] = rp[4];
    }
#pragma unroll
    for (int j = 0; j < 4; j++) {
      const float* wp = wl + ic * 384 + (og * 4 + j) * 12;
      float4 wA = *(const float4*)wp;
      float4 wB = *(const float4*)(wp + 4);
      float w8 = wp[8];
      float wr[9] = {wA.x, wA.y, wA.z, wA.w, wB.x, wB.y, wB.z, wB.w, w8};
#pragma unroll
      for (int py = 0; py < 2; py++)
#pragma unroll
        for (int px = 0; px < 2; px++) {
          float c = acc[j][py * 2 + px];
#pragma unroll
          for (int ky = 0; ky < 3; ky++)
#pragma unroll
            for (int kx = 0; kx < 3; kx++)
              c = fmaf(win[(2 * py + ky) * 5 + (2 * px + kx)], wr[ky * 3 + kx], c);
          acc[j][py * 2 + px] = c;
        }
    }
  }
#pragma unroll
  for (int j = 0; j < 4; j++) {
    int oc = og * 4 + j;
    float sc = g[oc] * BN_SCALE, bsj = bb[oc];
    float m = -1e30f;
#pragma unroll
    for (int p = 0; p < 4; p++) m = fmaxf(m, fmaf(acc[j][p], sc, bsj));
    out[(size_t)img * 2048 + oc * 64 + (OY0 + oyl) * 8 + oxl] = fmaxf(m, 0.f);
  }
}

// Layer 2: 32->64ch, 8x8 -> pool 4x4. Grid 1000 (img x 4 pooled-rows), 64 thr.
// lane = oc: windows wave-uniform (broadcast), weights coalesced from w2t.
__global__ void k_conv2(const float* __restrict__ a1, const float* __restrict__ w2t,
                        const float* __restrict__ g2, const float* __restrict__ b2,
                        float* __restrict__ a2) {
  __shared__ float sA[32 * 4 * 12];   // 6 KB: 4 input rows, col+1, stride 12
  int b = blockIdx.x;
  int img = b >> 2, oy = b & 3;
  int R0 = 2 * oy - 1;
  int t = threadIdx.x;
  const float* ap = a1 + (size_t)img * 2048;
  for (int i = t; i < 1536; i += 64) {
    int c = i % 12; int r = (i / 12) & 3; int ic = i / 48;
    int gr = R0 + r, gc = c - 1;
    sA[i] = (c >= 1 && c <= 8 && gr >= 0 && gr < 8) ? ap[ic * 64 + gr * 8 + gc] : 0.f;
  }
  __syncthreads();

  int oc = t;   // 64 lanes = 64 oc
  float cnv[16];
#pragma unroll
  for (int p = 0; p < 16; p++) cnv[p] = 0.f;
  for (int ic = 0; ic < 32; ic++) {
    float win[4][12];
#pragma unroll
    for (int r = 0; r < 4; r++) {
      const float4* rp = (const float4*)(sA + ic * 48 + r * 12);
      float4 u = rp[0], v = rp[1], z = rp[2];
      win[r][0] = u.x; win[r][1] = u.y; win[r][2] = u.z; win[r][3] = u.w;
      win[r][4] = v.x; win[r][5] = v.y; win[r][6] = v.z; win[r][7] = v.w;
      win[r][8] = z.x; win[r][9] = z.y; win[r][10] = z.z; win[r][11] = z.w;
    }
    const float* wp = w2t + ic * 576 + oc;
    float wr[9];
#pragma unroll
    for (int k = 0; k < 9; k++) wr[k] = wp[k * 64];
#pragma unroll
    for (int cy = 0; cy < 2; cy++)
#pragma unroll
      for (int cx = 0; cx < 8; cx++) {
        float c = cnv[cy * 8 + cx];
#pragma unroll
        for (int ky = 0; ky < 3; ky++)
#pragma unroll
          for (int kx = 0; kx < 3; kx++)
            c = fmaf(win[cy + ky][cx + kx], wr[ky * 3 + kx], c);
        cnv[cy * 8 + cx] = c;
      }
  }
  float sc = g2[oc] * BN_SCALE, bsj = b2[oc];
#pragma unroll
  for (int px = 0; px < 4; px++) {
    float m = -1e30f;
#pragma unroll
    for (int cy = 0; cy < 2; cy++)
#pragma unroll
      for (int dx = 0; dx < 2; dx++)
        m = fmaxf(m, fmaf(cnv[cy * 8 + 2 * px + dx], sc, bsj));
    a2[(size_t)img * 1024 + oc * 16 + oy * 4 + px] = fmaxf(m, 0.f);
  }
}

// Layer 3: 64->128ch, 4x4 -> pool 2x2. Grid 1000 (img x 2 oc-half x 2 prow), 64 thr.
__global__ void k_conv3(const float* __restrict__ a2, const float* __restrict__ w3t,
                        const float* __restrict__ g3, const float* __restrict__ b3,
                        float* __restrict__ a3) {
  __shared__ float sB[64 * 4 * 8];   // 8 KB
  int b = blockIdx.x;
  int img = b >> 2, sub = b & 3;
  int och = sub >> 1, prow = sub & 1;
  int R0 = 2 * prow - 1;
  int t = threadIdx.x;
  const float* ap = a2 + (size_t)img * 1024;
  for (int i = t; i < 2048; i += 64) {
    int c = i & 7; int r = (i >> 3) & 3; int ic = i >> 5;
    int gr = R0 + r, gc = c - 1;
    sB[i] = (c >= 1 && c <= 4 && gr >= 0 && gr < 4) ? ap[ic * 16 + gr * 4 + gc] : 0.f;
  }
  __syncthreads();

  int oc = och * 64 + t;
  float cnv[8];
#pragma unroll
  for (int p = 0; p < 8; p++) cnv[p] = 0.f;
  for (int ic = 0; ic < 64; ic++) {
    float win[4][6];
#pragma unroll
    for (int r = 0; r < 4; r++) {
      const float* rp = sB + ic * 32 + r * 8;
      float4 u = *(const float4*)rp;
      float2 v = *(const float2*)(rp + 4);
      win[r][0] = u.x; win[r][1] = u.y; win[r][2] = u.z; win[r][3] = u.w;
      win[r][4] = v.x; win[r][5] = v.y;
    }
    const float* wp = w3t + ic * 1152 + oc;
    float wr[9];
#pragma unroll
    for (int k = 0; k < 9; k++) wr[k] = wp[k * 128];
#pragma unroll
    for (int cy = 0; cy < 2; cy++)
#pragma unroll
      for (int cx = 0; cx < 4; cx++) {
        float c = cnv[cy * 4 + cx];
#pragma unroll
        for (int ky = 0; ky < 3; ky++)
#pragma unroll
          for (int kx = 0; kx < 3; kx++)
            c = fmaf(win[cy + ky][cx + kx], wr[ky * 3 + kx], c);
        cnv[cy * 4 + cx] = c;
      }
  }
  float sc = g3[oc] * BN_SCALE, bsj = b3[oc];
#pragma unroll
  for (int pc = 0; pc < 2; pc++) {
    float m = -1e30f;
#pragma unroll
    for (int cy = 0; cy < 2; cy++)
#pragma unroll
      for (int dx = 0; dx < 2; dx++)
        m = fmaxf(m, fmaf(cnv[cy * 4 + 2 * pc + dx], sc, bsj));
    a3[(size_t)img * 512 + oc * 4 + prow * 2 + pc] = fmaxf(m, 0.f);
  }
}

// Layer 4: 128->256ch, 2x2 -> pool 1x1 -> feats. Grid 1000 (img x 4 oc-qtr), 64 thr.
__global__ void k_conv4(const float* __restrict__ a3, const float* __restrict__ w4t,
                        const float* __restrict__ g4, const float* __restrict__ b4,
                        float* __restrict__ feats) {
  __shared__ float sIn[512];
  int b = blockIdx.x;
  int img = b >> 2, og = b & 3;
  int t = threadIdx.x;
  for (int i = t; i < 512; i += 64) sIn[i] = a3[(size_t)img * 512 + i];
  __syncthreads();

  int oc = og * 64 + t;
  float acc[4] = {0.f, 0.f, 0.f, 0.f};
  for (int ic = 0; ic < 128; ic++) {
    float4 iv = *(const float4*)(sIn + ic * 4);
    const float* wp = w4t + ic * 2304 + oc;
    float wr[9];
#pragma unroll
    for (int k = 0; k < 9; k++) wr[k] = wp[k * 256];
#pragma unroll
    for (int py = 0; py < 2; py++)
#pragma unroll
      for (int px = 0; px < 2; px++) {
        float c = acc[py * 2 + px];
        c = fmaf(iv.x, wr[(1 - py) * 3 + (1 - px)], c);
        c = fmaf(iv.y, wr[(1 - py) * 3 + (2 - px)], c);
        c = fmaf(iv.z, wr[(2 - py) * 3 + (1 - px)], c);
        c = fmaf(iv.w, wr[(2 - py) * 3 + (2 - px)], c);
        acc[py * 2 + px] = c;
      }
  }
  float sc = g4[oc] * BN_SCALE, bsj = b4[oc];
  float m = -1e30f;
#pragma unroll
  for (int p = 0; p < 4; p++) m = fmaxf(m, fmaf(acc[p], sc, bsj));
  feats[(size_t)img * 256 + oc] = fmaxf(m, 0.f);
}

// e[nk,c] = dot(feats[nk,:], trans_w[c,:]) + trans_b[c]
__global__ void k_e(const float* __restrict__ feats, const float* __restrict__ tw,
                    const float* __restrict__ tb, float* __restrict__ e) {
  int nk = blockIdx.x;
  int c = threadIdx.x;
  __shared__ float sf[256];
  sf[c] = feats[nk * 256 + c];
  __syncthreads();
  const float4* a = (const float4*)(tw + (size_t)c * 256);
  const float4* b = (const float4*)sf;
  float acc = tb[c];
  for (int d = 0; d < 64; d++) {
    float4 x = a[d], y = b[d];
    acc += x.x * y.x + x.y * y.y + x.z * y.z + x.w * y.w;
  }
  e[nk * 256 + c] = acc;
}

// 3-iter routing; 10 blocks. e-rows register-cached; batched reductions.
__global__ void k_routing(const float* __restrict__ e, float* __restrict__ proto) {
  int n = blockIdx.x;
  __shared__ float sb[10], sdc[10], red[4], red2[40];
  __shared__ float sfac;
  int t = threadIdx.x;
  int lane = t & 63, wid = t >> 6;
  float ek[10];
#pragma unroll
  for (int k = 0; k < 10; k++) ek[k] = e[n * 2560 + k * 256 + t];
  if (t < 10) sb[t] = 0.f;
  __syncthreads();
  float cd = 0.f;
  for (int iter = 0; iter < 3; iter++) {
    if (t == 0) {
      float mx = sb[0];
      for (int k = 1; k < 10; k++) mx = fmaxf(mx, sb[k]);
      float sum = 0.f;
      for (int k = 0; k < 10; k++) { float ex = expf(sb[k] - mx); sdc[k] = ex; sum += ex; }
      float inv = 1.f / sum;
      for (int k = 0; k < 10; k++) sdc[k] *= inv;
    }
    __syncthreads();
    cd = 0.f;
#pragma unroll
    for (int k = 0; k < 10; k++) cd = fmaf(sdc[k], ek[k], cd);
    float ss = cd * cd;
#pragma unroll
    for (int off = 32; off > 0; off >>= 1) ss += __shfl_down(ss, off, 64);
    if (lane == 0) red[wid] = ss;
    __syncthreads();
    if (t == 0) {
      float tot = red[0] + red[1] + red[2] + red[3];
      sfac = sqrtf(tot) / (tot + 1.f);
    }
    __syncthreads();
    cd *= sfac;
    float p[10];
#pragma unroll
    for (int k = 0; k < 10; k++) p[k] = cd * ek[k];
#pragma unroll
    for (int off = 32; off > 0; off >>= 1)
#pragma unroll
      for (int k = 0; k < 10; k++) p[k] += __shfl_down(p[k], off, 64);
    if (lane == 0)
#pragma unroll
      for (int k = 0; k < 10; k++) red2[k * 4 + wid] = p[k];
    __syncthreads();
    if (t < 10) sb[t] += red2[t * 4] + red2[t * 4 + 1] + red2[t * 4 + 2] + red2[t * 4 + 3];
    __syncthreads();
  }
  proto[n * 256 + t] = cd;
}

// t1[n,h,e] += sum_{c chunk} proto[n,c]*bil_w[h,c,e]. Grid 800 (h x 8 chunks).
__global__ void k_t1(const float* __restrict__ proto, const float* __restrict__ bw,
                     float* __restrict__ t1) {
  int b = blockIdx.x;
  int h = b >> 3, c0 = (b & 7) * 32;
  int e = threadIdx.x;
  __shared__ float sp[320];
  for (int i = e; i < 320; i += 256) {
    int n = i >> 5, cl = i & 31;
    sp[i] = proto[n * 256 + c0 + cl];
  }
  __syncthreads();
  float acc[10];
#pragma unroll
  for (int n = 0; n < 10; n++) acc[n] = 0.f;
  const float* wp = bw + ((size_t)h * 256 + c0) * 256 + e;
#pragma unroll 4
  for (int cl = 0; cl < 32; cl++) {
    float wv = wp[(size_t)cl * 256];
#pragma unroll
    for (int n = 0; n < 10; n++) acc[n] = fmaf(sp[n * 32 + cl], wv, acc[n]);
  }
#pragma unroll
  for (int n = 0; n < 10; n++)
    atomicAdd(&t1[((size_t)n * 100 + h) * 256 + e], acc[n]);
}

// Per-q: s[n] = sum_h relu(dot(t1[n,h,:], qf[q,:]))*sw[h] + sb, then log_softmax.
// Grid 150 (q), 256 thr = 4 waves (each 25 h values, all 10 n).
__global__ void k_score(const float* __restrict__ t1, const float* __restrict__ qf,
                        const float* __restrict__ sw, const float* __restrict__ sbp,
                        float* __restrict__ out) {
  int q = blockIdx.x;
  int t = threadIdx.x, lane = t & 63, wid = t >> 6;
  __shared__ float sred[40];
  float4 qv = *(const float4*)(qf + q * 256 + lane * 4);
  float accn[10];
#pragma unroll
  for (int n = 0; n < 10; n++) accn[n] = 0.f;
  for (int h = wid * 25; h < wid * 25 + 25; h++) {
    float swh = sw[h];
#pragma unroll
    for (int n = 0; n < 10; n++) {
      float4 tv = *(const float4*)(t1 + ((size_t)n * 100 + h) * 256 + lane * 4);
      float p = tv.x * qv.x + tv.y * qv.y + tv.z * qv.z + tv.w * qv.w;
#pragma unroll
      for (int off = 32; off > 0; off >>= 1) p += __shfl_down(p, off, 64);
      if (lane == 0) accn[n] = fmaf(fmaxf(p, 0.f), swh, accn[n]);
    }
  }
  if (lane == 0)
#pragma unroll
    for (int n = 0; n < 10; n++) sred[wid * 10 + n] = accn[n];
  __syncthreads();
  if (t == 0) {
    float s[10];
    float mx = -1e30f;
    for (int n = 0; n < 10; n++) {
      s[n] = sred[n] + sred[10 + n] + sred[20 + n] + sred[30 + n] + sbp[0];
      mx = fmaxf(mx, s[n]);
    }
    float sum = 0.f;
    for (int n = 0; n < 10; n++) sum += expf(s[n] - mx);
    float lse = mx + logf(sum);
    for (int n = 0; n < 10; n++) out[q * 10 + n] = s[n] - lse;
  }
}

extern "C" void kernel_launch(void* const* d_in, const int* in_sizes, int n_in,
                              void* d_out, int out_size, void* d_ws, size_t ws_size,
                              hipStream_t stream) {
  const float* support = (const float*)d_in[0];
  const float* query   = (const float*)d_in[1];
  const float* conv_w[5]; const float* bn_g[5]; const float* bn_b[5];
  for (int i = 0; i < 5; i++) {
    conv_w[i] = (const float*)d_in[2 + 3 * i];
    bn_g[i]   = (const float*)d_in[3 + 3 * i];
    bn_b[i]   = (const float*)d_in[4 + 3 * i];
  }
  const float* trans_w = (const float*)d_in[17];
  const float* trans_b = (const float*)d_in[18];
  const float* bil_w   = (const float*)d_in[19];
  const float* score_w = (const float*)d_in[20];
  const float* score_b = (const float*)d_in[21];
  float* out = (float*)d_out;
  float* ws = (float*)d_ws;

  // disjoint workspace regions (22.9 MB total)
  float* a0    = ws;                  // (250,16,32,32) = 4,096,000
  float* a1    = ws + 4096000;        // (250,32,8,8)   =   512,000
  float* a2    = ws + 4608000;        // (250,64,4,4)   =   256,000
  float* a3    = ws + 4864000;        // (250,128,2,2)  =   128,000
  float* feats = ws + 4992000;        // (250,256)      =    64,000
  float* e_buf = ws + 5056000;        // (100,256)      =    25,600
  float* proto = ws + 5081600;        // (10,256)       =     2,560
  float* t1    = ws + 5084160;        // (10,100,256)   =   256,000
  float* w2t   = ws + 5340160;        //    18,432
  float* w3t   = ws + 5358592;        //    73,728
  float* w4t   = ws + 5432320;        //   294,912

  k_pre<<<2512, 256, 0, stream>>>(conv_w[2], conv_w[3], conv_w[4], w2t, w3t, w4t, t1);
  k_block0<<<1000, 256, 0, stream>>>(support, query, conv_w[0], bn_g[0], bn_b[0], a0);
  k_block1<<<500, 256, 0, stream>>>(a0, conv_w[1], bn_g[1], bn_b[1], a1);
  k_conv2<<<1000, 64, 0, stream>>>(a1, w2t, bn_g[2], bn_b[2], a2);
  k_conv3<<<1000, 64, 0, stream>>>(a2, w3t, bn_g[3], bn_b[3], a3);
  k_conv4<<<1000, 64, 0, stream>>>(a3, w4t, bn_g[4], bn_b[4], feats);
  k_e<<<100, 256, 0, stream>>>(feats, trans_w, trans_b, e_buf);
  k_routing<<<10, 256, 0, stream>>>(e_buf, proto);
  k_t1<<<800, 256, 0, stream>>>(proto, bil_w, t1);
  k_score<<<150, 256, 0, stream>>>(t1, feats + 100 * 256, score_w, score_b, out);
}